// Round 3
// baseline (1804.318 us; speedup 1.0000x reference)
//
#include <hip/hip_runtime.h>
#include <stdint.h>

static constexpr int BB = 8;
static constexpr int SS = 4096;
static constexpr int HH = 1024;

// ---- monotonic float<->uint mapping (order-preserving, for atomicMax) ----
__device__ __forceinline__ unsigned f2mono(float f) {
    unsigned u = __float_as_uint(f);
    return (u & 0x80000000u) ? ~u : (u | 0x80000000u);
}
__device__ __forceinline__ float mono2f(unsigned u) {
    return __uint_as_float((u & 0x80000000u) ? (u ^ 0x80000000u) : ~u);
}

// ---- blit: out0 = hidden_states (SDMA memcpy is ~1 TB/s; this hits ~6) ----
__global__ void blit(const float4* __restrict__ s, float4* __restrict__ d, int n4) {
    int i = blockIdx.x * blockDim.x + threadIdx.x;
    int stride = gridDim.x * blockDim.x;
    for (; i < n4; i += stride) d[i] = s[i];
}

// ---- kernel I: zero scores, copy previous_mask -> out_mask ----
__global__ void k_init(const float* __restrict__ prev, unsigned* __restrict__ scores,
                       float* __restrict__ out_mask) {
    int i = blockIdx.x * blockDim.x + threadIdx.x;
    if (i < BB * SS) { scores[i] = 0u; out_mask[i] = prev[i]; }
}

// ---- kernel 0: amin over attention_mask, bmax over bias ----
__global__ void reduce_ab(const float* __restrict__ a, const float* __restrict__ bias,
                          float* __restrict__ amin_out, float* __restrict__ bmax_out) {
    __shared__ float red[256];
    int t = threadIdx.x;
    float mn = 1e30f;
    const float4* a4 = (const float4*)a;
    for (int i = t; i < BB * SS / 4; i += 256) {
        float4 v = a4[i];
        mn = fminf(mn, fminf(fminf(v.x, v.y), fminf(v.z, v.w)));
    }
    red[t] = mn; __syncthreads();
    for (int o = 128; o; o >>= 1) { if (t < o) red[t] = fminf(red[t], red[t + o]); __syncthreads(); }
    if (t == 0) *amin_out = red[0];
    __syncthreads();
    float mx = -1e30f;
    for (int i = t; i < HH; i += 256) mx = fmaxf(mx, bias[i]);
    red[t] = mx; __syncthreads();
    for (int o = 128; o; o >>= 1) { if (t < o) red[t] = fmaxf(red[t], red[t + o]); __syncthreads(); }
    if (t == 0) *bmax_out = red[0];
}

// ---- kernel A: per-batch-row compaction (one 64-lane wave per row) ----
__global__ void compact(const float* __restrict__ prev, const float* __restrict__ a,
                        int* __restrict__ kept_src,
                        int* __restrict__ n_keep, int* __restrict__ zcnt) {
    int b = blockIdx.x;
    int lane = threadIdx.x;          // 0..63, one wave
    const float* pm = prev + (size_t)b * SS;
    const float* am = a + (size_t)b * SS;
    int* ks = kept_src + (size_t)b * SS;

    int base_s = lane * (SS / 64);
    int cnt = 0, zc = 0;
    for (int i = 0; i < SS / 64; ++i) {
        if (pm[base_s + i] > 0.5f) {
            cnt++;
            if (am[base_s + i] == 0.0f) zc++;
        }
    }
    int incl = cnt;
    for (int o = 1; o < 64; o <<= 1) {
        int v = __shfl_up(incl, o);
        if (lane >= o) incl += v;
    }
    int total = __shfl(incl, 63);
    int pos = incl - cnt;
    for (int i = 0; i < SS / 64; ++i) {
        if (pm[base_s + i] > 0.5f) ks[pos++] = base_s + i;
    }
    for (int o = 1; o < 64; o <<= 1) zc += __shfl_xor(zc, o);
    if (lane == 0) { n_keep[b] = total; zcnt[b] = zc; }
    for (int j = total + lane; j < SS; j += 64) ks[j] = 0;   // pad with safe dummy
}

// ---- kernel B: gathered GEMM + bias + max-over-columns -> atomicMax(score) ----
// LDS-free, barrier-free. Block = 32 rows x 256 cols, 4 waves; wave w owns rows
// w*8..w*8+7 (wave-uniform broadcast loads), lane owns 4 cols. acc 8x4.
// 2-stage ping-pong: stage loads (8 uniform A float4 + 4 W float4) fly under
// the other stage's 128 FMAs. Strict k-ascending fmaf order (bit-stable).
#define MT 32
#define NT 256
__global__ __launch_bounds__(256, 1) void gemm_max(
    const float* __restrict__ hs, const float* __restrict__ W,
    const float* __restrict__ bias, const int* __restrict__ kept_src,
    const int* __restrict__ n_keep, unsigned* __restrict__ scores) {
    int mt = blockIdx.x, nt = blockIdx.y, b = blockIdx.z;
    int nk = n_keep[b];
    int m0 = mt * MT;
    if (m0 >= nk) return;

    int t = threadIdx.x, lane = t & 63, w = t >> 6;
    int n0 = nt * NT;

    const float* arow[8];
#pragma unroll
    for (int r = 0; r < 8; ++r) {
        int src = kept_src[(size_t)b * SS + m0 + w * 8 + r];   // wave-uniform
        arow[r] = hs + ((size_t)b * SS + (size_t)src) * HH;
    }
    const float* wcol = W + n0 + lane * 4;

    float acc[8][4];
#pragma unroll
    for (int r = 0; r < 8; ++r)
#pragma unroll
        for (int c = 0; c < 4; ++c) acc[r][c] = 0.f;

    float4 aC[8], aN[8], wC[4], wN[4];

#define LOAD_STAGE(AV, WV, K4)                                             \
    {                                                                      \
        int _k4 = (K4);                                                    \
        _Pragma("unroll")                                                  \
        for (int r = 0; r < 8; ++r)                                        \
            AV[r] = *(const float4*)(arow[r] + _k4 * 4);                   \
        _Pragma("unroll")                                                  \
        for (int kk = 0; kk < 4; ++kk)                                     \
            WV[kk] = *(const float4*)(wcol + (size_t)(_k4 * 4 + kk) * HH); \
    }

#define COMPUTE_STAGE(AV, WV)                                              \
    {                                                                      \
        _Pragma("unroll")                                                  \
        for (int kk = 0; kk < 4; ++kk) {                                   \
            float wv0 = WV[kk].x, wv1 = WV[kk].y, wv2 = WV[kk].z, wv3 = WV[kk].w; \
            _Pragma("unroll")                                              \
            for (int r = 0; r < 8; ++r) {                                  \
                float av = ((const float*)&AV[r])[kk];                     \
                acc[r][0] = fmaf(av, wv0, acc[r][0]);                      \
                acc[r][1] = fmaf(av, wv1, acc[r][1]);                      \
                acc[r][2] = fmaf(av, wv2, acc[r][2]);                      \
                acc[r][3] = fmaf(av, wv3, acc[r][3]);                      \
            }                                                              \
        }                                                                  \
    }

    LOAD_STAGE(aC, wC, 0)
    for (int k4 = 0; k4 < HH / 4; k4 += 2) {
        LOAD_STAGE(aN, wN, k4 + 1)
        COMPUTE_STAGE(aC, wC)
        LOAD_STAGE(aC, wC, (k4 + 2) & (HH / 4 - 1))   // wraps at end: harmless
        COMPUTE_STAGE(aN, wN)
    }

    float4 bia = *(const float4*)(bias + n0 + lane * 4);
#pragma unroll
    for (int r = 0; r < 8; ++r) {
        float v = fmaxf(fmaxf(acc[r][0] + bia.x, acc[r][1] + bia.y),
                        fmaxf(acc[r][2] + bia.z, acc[r][3] + bia.w));
        for (int o = 32; o; o >>= 1) v = fmaxf(v, __shfl_xor(v, o));
        if (lane == 0)
            atomicMax(scores + (size_t)b * SS + m0 + w * 8 + r, f2mono(v));
    }
#undef LOAD_STAGE
#undef COMPUTE_STAGE
}

// ---- kernel C: exact stable top-k via rank counting + scatter ----
__global__ __launch_bounds__(1024) void topk_rank(
    const float* __restrict__ a, const int* __restrict__ kept_src,
    const unsigned* __restrict__ scores, const int* __restrict__ n_keep,
    const int* __restrict__ zcnt, const float* __restrict__ amin_p,
    const float* __restrict__ bmax_p, float* __restrict__ out_mask) {
    __shared__ unsigned long long keys[SS];   // 32 KiB
    int b = blockIdx.x, ch = blockIdx.y, t = threadIdx.x;
    int nk = n_keep[b];
    float amin = *amin_p, bmax = *bmax_p;
    int z = zcnt[b] + ((amin == 0.0f) ? (SS - nk) : 0);
    int tk = (int)((float)z * 0.8f);
    if (tk < 1) tk = 1;
    float padv = (bmax + amin * 100.0f) + amin;

    const int* ks = kept_src + (size_t)b * SS;
    const unsigned* sc = scores + (size_t)b * SS;
    const float* arow = a + (size_t)b * SS;

    for (int j = t; j < SS; j += 1024) {
        float sval;
        if (j < nk) {
            float core = mono2f(sc[j]);
            float av = arow[ks[j]];
            sval = (core + av * 100.0f) + av;     // replicate reference op order
        } else {
            sval = padv;
        }
        keys[j] = ((unsigned long long)(~f2mono(sval)) << 32) | (unsigned)j;
    }
    __syncthreads();

    int j = ch * 1024 + t;
    unsigned long long mykey = keys[j];
    int rank = 0;
#pragma unroll 8
    for (int i = 0; i < SS; ++i) rank += (keys[i] < mykey) ? 1 : 0;

    if (j < nk) out_mask[(size_t)b * SS + ks[j]] = (rank < tk) ? 1.0f : 0.0f;
}

extern "C" void kernel_launch(void* const* d_in, const int* in_sizes, int n_in,
                              void* d_out, int out_size, void* d_ws, size_t ws_size,
                              hipStream_t stream) {
    const float* hs   = (const float*)d_in[0];   // [8,4096,1024]
    const float* am   = (const float*)d_in[1];   // [8,4096]
    const float* pmsk = (const float*)d_in[2];   // [8,4096]
    const float* W    = (const float*)d_in[3];   // [1024,1024]
    const float* bias = (const float*)d_in[4];   // [1024]

    float* out0 = (float*)d_out;                       // new_ret
    float* out1 = out0 + (size_t)BB * SS * HH;         // new_mask

    char* ws = (char*)d_ws;
    int*      kept_src = (int*)ws;                                // 128 KiB
    unsigned* scores   = (unsigned*)(ws + (size_t)BB * SS * 4);   // 128 KiB
    int*      nkeep    = (int*)(ws + (size_t)2 * BB * SS * 4);
    int*      zc       = nkeep + BB;
    float*    amin_p   = (float*)(zc + BB);
    float*    bmax_p   = amin_p + 1;

    // output 0: new_ret == hidden_states exactly (kernel blit, not SDMA)
    hipLaunchKernelGGL(blit, dim3(4096), dim3(256), 0, stream,
                       (const float4*)hs, (float4*)out0, BB * SS * HH / 4);

    hipLaunchKernelGGL(k_init, dim3(BB * SS / 256), dim3(256), 0, stream,
                       pmsk, scores, out1);
    hipLaunchKernelGGL(reduce_ab, dim3(1), dim3(256), 0, stream, am, bias, amin_p, bmax_p);
    hipLaunchKernelGGL(compact, dim3(BB), dim3(64), 0, stream,
                       pmsk, am, kept_src, nkeep, zc);
    hipLaunchKernelGGL(gemm_max, dim3(SS / MT, HH / NT, BB), dim3(256), 0, stream,
                       hs, W, bias, kept_src, nkeep, scores);
    hipLaunchKernelGGL(topk_rank, dim3(BB, SS / 1024), dim3(1024), 0, stream,
                       am, kept_src, scores, nkeep, zc, amin_p, bmax_p, out1);
}

// Round 4
// 894.978 us; speedup vs baseline: 2.0160x; 2.0160x over previous
//
#include <hip/hip_runtime.h>
#include <stdint.h>

static constexpr int BB = 8;
static constexpr int SS = 4096;
static constexpr int HH = 1024;

// ---- monotonic float<->uint mapping (order-preserving, for atomicMax) ----
__device__ __forceinline__ unsigned f2mono(float f) {
    unsigned u = __float_as_uint(f);
    return (u & 0x80000000u) ? ~u : (u | 0x80000000u);
}
__device__ __forceinline__ float mono2f(unsigned u) {
    return __uint_as_float((u & 0x80000000u) ? (u ^ 0x80000000u) : ~u);
}

// ---- blit: out0 = hidden_states ----
__global__ void blit(const float4* __restrict__ s, float4* __restrict__ d, int n4) {
    int i = blockIdx.x * blockDim.x + threadIdx.x;
    int stride = gridDim.x * blockDim.x;
    for (; i < n4; i += stride) d[i] = s[i];
}

// ---- kernel I: zero scores, copy previous_mask -> out_mask ----
__global__ void k_init(const float* __restrict__ prev, unsigned* __restrict__ scores,
                       float* __restrict__ out_mask) {
    int i = blockIdx.x * blockDim.x + threadIdx.x;
    if (i < BB * SS) { scores[i] = 0u; out_mask[i] = prev[i]; }
}

// ---- kernel 0: amin over attention_mask, bmax over bias ----
__global__ void reduce_ab(const float* __restrict__ a, const float* __restrict__ bias,
                          float* __restrict__ amin_out, float* __restrict__ bmax_out) {
    __shared__ float red[256];
    int t = threadIdx.x;
    float mn = 1e30f;
    const float4* a4 = (const float4*)a;
    for (int i = t; i < BB * SS / 4; i += 256) {
        float4 v = a4[i];
        mn = fminf(mn, fminf(fminf(v.x, v.y), fminf(v.z, v.w)));
    }
    red[t] = mn; __syncthreads();
    for (int o = 128; o; o >>= 1) { if (t < o) red[t] = fminf(red[t], red[t + o]); __syncthreads(); }
    if (t == 0) *amin_out = red[0];
    __syncthreads();
    float mx = -1e30f;
    for (int i = t; i < HH; i += 256) mx = fmaxf(mx, bias[i]);
    red[t] = mx; __syncthreads();
    for (int o = 128; o; o >>= 1) { if (t < o) red[t] = fmaxf(red[t], red[t + o]); __syncthreads(); }
    if (t == 0) *bmax_out = red[0];
}

// ---- kernel A: per-batch-row compaction (one 64-lane wave per row) ----
__global__ void compact(const float* __restrict__ prev, const float* __restrict__ a,
                        int* __restrict__ kept_src,
                        int* __restrict__ n_keep, int* __restrict__ zcnt) {
    int b = blockIdx.x;
    int lane = threadIdx.x;          // 0..63, one wave
    const float* pm = prev + (size_t)b * SS;
    const float* am = a + (size_t)b * SS;
    int* ks = kept_src + (size_t)b * SS;

    int base_s = lane * (SS / 64);
    int cnt = 0, zc = 0;
    for (int i = 0; i < SS / 64; ++i) {
        if (pm[base_s + i] > 0.5f) {
            cnt++;
            if (am[base_s + i] == 0.0f) zc++;
        }
    }
    int incl = cnt;
    for (int o = 1; o < 64; o <<= 1) {
        int v = __shfl_up(incl, o);
        if (lane >= o) incl += v;
    }
    int total = __shfl(incl, 63);
    int pos = incl - cnt;
    for (int i = 0; i < SS / 64; ++i) {
        if (pm[base_s + i] > 0.5f) ks[pos++] = base_s + i;
    }
    for (int o = 1; o < 64; o <<= 1) zc += __shfl_xor(zc, o);
    if (lane == 0) { n_keep[b] = total; zcnt[b] = zc; }
    for (int j = total + lane; j < SS; j += 64) ks[j] = 0;   // pad with safe dummy
}

// ---- kernel B: gathered GEMM + bias + max-over-columns -> atomicMax(score) ----
// Round-1 structure + double-buffered LDS (1 barrier/chunk, load issued a full
// chunk early) + conflict-free staging writes.
// Block: 32 rows x 256 cols, 256 threads (4 waves). Wave w computes rows
// w*8..w*8+7 (wave-uniform LDS broadcast), lane owns 4 cols. acc[8][4].
#define MT 32
#define NT 256
#define BK 32
__global__ __launch_bounds__(256) void gemm_max(
    const float* __restrict__ hs, const float* __restrict__ W,
    const float* __restrict__ bias, const int* __restrict__ kept_src,
    const int* __restrict__ n_keep, unsigned* __restrict__ scores) {
    int mt = blockIdx.x, nt = blockIdx.y, b = blockIdx.z;
    int nk = n_keep[b];
    int m0 = mt * MT;
    if (m0 >= nk) return;

    __shared__ float A[2][BK][MT];   // 8 KB double buffer
    __shared__ int src[MT];
    int t = threadIdx.x, lane = t & 63, w = t >> 6;
    if (t < MT) src[t] = kept_src[(size_t)b * SS + m0 + t];
    __syncthreads();

    int sm  = t & 31;                // staging row (lanes -> 32 distinct banks)
    int skq = t >> 5;                // k-quad 0..7
    const float* arow = hs + ((size_t)b * SS + (size_t)src[sm]) * HH + skq * 4;
    int n0 = nt * NT;
    const float* wcol = W + n0 + lane * 4;

    float acc[8][4];
#pragma unroll
    for (int r = 0; r < 8; ++r)
#pragma unroll
        for (int c = 0; c < 4; ++c) acc[r][c] = 0.f;

    // prologue: stage chunk 0
    {
        float4 f = *(const float4*)(arow);
        A[0][skq * 4 + 0][sm] = f.x; A[0][skq * 4 + 1][sm] = f.y;
        A[0][skq * 4 + 2][sm] = f.z; A[0][skq * 4 + 3][sm] = f.w;
    }
    __syncthreads();

    for (int kc = 0; kc < HH / BK; ++kc) {
        int cur = kc & 1;
        float4 f;
        if (kc < HH / BK - 1)
            f = *(const float4*)(arow + (kc + 1) * BK);   // lands during compute

        const float* wk = wcol + (size_t)kc * BK * HH;
#pragma unroll 8
        for (int k = 0; k < BK; ++k) {
            float4 w4 = *(const float4*)wk;
            wk += HH;
            const float4* ap = (const float4*)(&A[cur][k][w * 8]);  // broadcast
            float4 a0 = ap[0], a1 = ap[1];
            float av[8] = {a0.x, a0.y, a0.z, a0.w, a1.x, a1.y, a1.z, a1.w};
#pragma unroll
            for (int r = 0; r < 8; ++r) {
                acc[r][0] = fmaf(av[r], w4.x, acc[r][0]);
                acc[r][1] = fmaf(av[r], w4.y, acc[r][1]);
                acc[r][2] = fmaf(av[r], w4.z, acc[r][2]);
                acc[r][3] = fmaf(av[r], w4.w, acc[r][3]);
            }
        }
        if (kc < HH / BK - 1) {
            int nx = cur ^ 1;
            A[nx][skq * 4 + 0][sm] = f.x; A[nx][skq * 4 + 1][sm] = f.y;
            A[nx][skq * 4 + 2][sm] = f.z; A[nx][skq * 4 + 3][sm] = f.w;
        }
        __syncthreads();
    }

    float4 bia = *(const float4*)(bias + n0 + lane * 4);
#pragma unroll
    for (int r = 0; r < 8; ++r) {
        float v = fmaxf(fmaxf(acc[r][0] + bia.x, acc[r][1] + bia.y),
                        fmaxf(acc[r][2] + bia.z, acc[r][3] + bia.w));
        for (int o = 32; o; o >>= 1) v = fmaxf(v, __shfl_xor(v, o));
        if (lane == 0)
            atomicMax(scores + (size_t)b * SS + m0 + w * 8 + r, f2mono(v));
    }
}

// ---- kernel C: exact stable top-k via rank counting + scatter ----
// grid (BB, 16), 256 threads: block ranks 256 elements against all 4096
// (ulonglong2 broadcast reads from LDS; 128 blocks spread across CUs).
__global__ __launch_bounds__(256) void topk_rank(
    const float* __restrict__ a, const int* __restrict__ kept_src,
    const unsigned* __restrict__ scores, const int* __restrict__ n_keep,
    const int* __restrict__ zcnt, const float* __restrict__ amin_p,
    const float* __restrict__ bmax_p, float* __restrict__ out_mask) {
    __shared__ unsigned long long keys[SS];   // 32 KiB
    int b = blockIdx.x, ch = blockIdx.y, t = threadIdx.x;
    int nk = n_keep[b];
    float amin = *amin_p, bmax = *bmax_p;
    int z = zcnt[b] + ((amin == 0.0f) ? (SS - nk) : 0);
    int tk = (int)((float)z * 0.8f);
    if (tk < 1) tk = 1;
    float padv = (bmax + amin * 100.0f) + amin;

    const int* ks = kept_src + (size_t)b * SS;
    const unsigned* sc = scores + (size_t)b * SS;
    const float* arow = a + (size_t)b * SS;

    for (int j = t; j < SS; j += 256) {
        float sval;
        if (j < nk) {
            float core = mono2f(sc[j]);
            float av = arow[ks[j]];
            sval = (core + av * 100.0f) + av;     // replicate reference op order
        } else {
            sval = padv;
        }
        keys[j] = ((unsigned long long)(~f2mono(sval)) << 32) | (unsigned)j;
    }
    __syncthreads();

    int j = ch * 256 + t;
    unsigned long long mykey = keys[j];
    int rank = 0;
    const ulonglong2* k2 = (const ulonglong2*)keys;
#pragma unroll 8
    for (int i = 0; i < SS / 2; ++i) {
        ulonglong2 kk = k2[i];                    // wave-uniform -> broadcast
        rank += (kk.x < mykey) ? 1 : 0;
        rank += (kk.y < mykey) ? 1 : 0;
    }
    if (j < nk) out_mask[(size_t)b * SS + ks[j]] = (rank < tk) ? 1.0f : 0.0f;
}

extern "C" void kernel_launch(void* const* d_in, const int* in_sizes, int n_in,
                              void* d_out, int out_size, void* d_ws, size_t ws_size,
                              hipStream_t stream) {
    const float* hs   = (const float*)d_in[0];   // [8,4096,1024]
    const float* am   = (const float*)d_in[1];   // [8,4096]
    const float* pmsk = (const float*)d_in[2];   // [8,4096]
    const float* W    = (const float*)d_in[3];   // [1024,1024]
    const float* bias = (const float*)d_in[4];   // [1024]

    float* out0 = (float*)d_out;                       // new_ret
    float* out1 = out0 + (size_t)BB * SS * HH;         // new_mask

    char* ws = (char*)d_ws;
    int*      kept_src = (int*)ws;                                // 128 KiB
    unsigned* scores   = (unsigned*)(ws + (size_t)BB * SS * 4);   // 128 KiB
    int*      nkeep    = (int*)(ws + (size_t)2 * BB * SS * 4);
    int*      zc       = nkeep + BB;
    float*    amin_p   = (float*)(zc + BB);
    float*    bmax_p   = amin_p + 1;

    // output 0: new_ret == hidden_states exactly
    hipLaunchKernelGGL(blit, dim3(2048), dim3(256), 0, stream,
                       (const float4*)hs, (float4*)out0, BB * SS * HH / 4);

    hipLaunchKernelGGL(k_init, dim3(BB * SS / 256), dim3(256), 0, stream,
                       pmsk, scores, out1);
    hipLaunchKernelGGL(reduce_ab, dim3(1), dim3(256), 0, stream, am, bias, amin_p, bmax_p);
    hipLaunchKernelGGL(compact, dim3(BB), dim3(64), 0, stream,
                       pmsk, am, kept_src, nkeep, zc);
    hipLaunchKernelGGL(gemm_max, dim3(SS / MT, HH / NT, BB), dim3(256), 0, stream,
                       hs, W, bias, kept_src, nkeep, scores);
    hipLaunchKernelGGL(topk_rank, dim3(BB, SS / 256), dim3(256), 0, stream,
                       am, kept_src, scores, nkeep, zc, amin_p, bmax_p, out1);
}